// Round 9
// baseline (189.976 us; speedup 1.0000x reference)
//
#include <hip/hip_runtime.h>

typedef _Float16 H16;
typedef _Float16 half8 __attribute__((ext_vector_type(8)));
typedef _Float16 half4 __attribute__((ext_vector_type(4)));
typedef float f32x4 __attribute__((ext_vector_type(4)));

// problem dims
constexpr int Bb = 2, S = 2048, D = 1024, NH = 16, HW = 64;
constexpr int M = Bb * S;  // 4096

// workspace layout (bytes)
constexpr size_t XH_OFF = 0;                               // [M][D] f16
constexpr size_t WT_OFF = XH_OFF + (size_t)M * D * 2;      // 3x [D(n)][D(k)] f16
constexpr size_t Q_OFF  = WT_OFF + 3ull * D * D * 2;       // [B][NH][S][HW] f16
constexpr size_t K_OFF  = Q_OFF + (size_t)M * D * 2;       // [B][NH][S][HW] f16
constexpr size_t VT_OFF = K_OFF + (size_t)M * D * 2;       // [B][NH][HW][S] f16

#define GLOAD_LDS16(g, l)                                        \
  __builtin_amdgcn_global_load_lds(                              \
      (const __attribute__((address_space(1))) void*)(g),        \
      (__attribute__((address_space(3))) void*)(l), 16, 0, 0)

// ---------------- x fp32 -> fp16 ----------------
__global__ __launch_bounds__(256) void cvt_x(const float* __restrict__ x,
                                             H16* __restrict__ xh) {
  size_t i = ((size_t)blockIdx.x * 256 + threadIdx.x) * 8;
  float4 a = *(const float4*)(x + i);
  float4 b = *(const float4*)(x + i + 4);
  half8 h = {(H16)a.x, (H16)a.y, (H16)a.z, (H16)a.w,
             (H16)b.x, (H16)b.y, (H16)b.z, (H16)b.w};
  *(half8*)(xh + i) = h;
}

// ---------------- W -> W^T fp16 (tiled transpose) ----------------
__global__ __launch_bounds__(256) void wt_cvt(const float* __restrict__ w0,
                                              const float* __restrict__ w1,
                                              const float* __restrict__ w2,
                                              H16* __restrict__ wt) {
  __shared__ H16 tile[64][65];
  const float* w = blockIdx.z == 0 ? w0 : blockIdx.z == 1 ? w1 : w2;
  H16* out = wt + (size_t)blockIdx.z * D * D;
  int t = threadIdx.x;
  int c = t & 63, r4 = t >> 6;
  int bx = blockIdx.x * 64, by = blockIdx.y * 64;
#pragma unroll 4
  for (int it = 0; it < 16; ++it) {
    int row = it * 4 + r4;
    tile[c][row] = (H16)w[(size_t)(by + row) * D + bx + c];
  }
  __syncthreads();
#pragma unroll 4
  for (int it = 0; it < 16; ++it) {
    int row = it * 4 + r4;
    out[(size_t)(bx + row) * D + by + c] = tile[row][c];
  }
}

// ---------------- fused QKV GEMM (fp16 MFMA, 128x128x32 tiles) ----------------
__global__ __launch_bounds__(256) void qkv_gemm(
    const H16* __restrict__ xh, const H16* __restrict__ wt,
    const float* __restrict__ bq, const float* __restrict__ bk,
    const float* __restrict__ bv, H16* __restrict__ qo, H16* __restrict__ ko,
    H16* __restrict__ vto) {
  __shared__ __align__(16) H16 As[128 * 32];
  __shared__ __align__(16) H16 Bs[128 * 32];
  const int z = blockIdx.z;
  const H16* w = wt + (size_t)z * D * D;
  const float* bias = z == 0 ? bq : z == 1 ? bk : bv;
  const int bm = blockIdx.y * 128, bn = blockIdx.x * 128;
  const int t = threadIdx.x;
  const int wave = t >> 6, lane = t & 63;
  const int g = lane >> 4, c = lane & 15;
  const int wm = (wave >> 1) * 64, wn = (wave & 1) * 64;

  f32x4 acc[4][4] = {};

  for (int kk = 0; kk < D; kk += 32) {
#pragma unroll
    for (int rnd = 0; rnd < 2; ++rnd) {
      int cid = rnd * 256 + t;
      int row = cid >> 2, k0 = (cid & 3) * 8;
      GLOAD_LDS16(&xh[(size_t)(bm + row) * D + kk + k0], &As[cid * 8]);
      GLOAD_LDS16(&w[(size_t)(bn + row) * D + kk + k0], &Bs[cid * 8]);
    }
    __syncthreads();
    half8 af[4], bf[4];
#pragma unroll
    for (int i = 0; i < 4; ++i) {
      af[i] = *(const half8*)&As[(wm + i * 16 + c) * 32 + g * 8];
      bf[i] = *(const half8*)&Bs[(wn + i * 16 + c) * 32 + g * 8];
    }
#pragma unroll
    for (int i = 0; i < 4; ++i)
#pragma unroll
      for (int j = 0; j < 4; ++j)
        acc[i][j] =
            __builtin_amdgcn_mfma_f32_16x16x32_f16(af[i], bf[j], acc[i][j], 0, 0, 0);
    __syncthreads();
  }

#pragma unroll
  for (int i = 0; i < 4; ++i) {
#pragma unroll
    for (int j = 0; j < 4; ++j) {
      int coln = bn + wn + j * 16 + c;
      float bse = bias[coln];
      int h = coln >> 6, wcol = coln & 63;
      if (z == 2) {
        int row0 = bm + wm + i * 16 + g * 4;
        int bbx = row0 >> 11, s0 = row0 & (S - 1);
        half4 v4 = {(H16)(acc[i][j][0] + bse), (H16)(acc[i][j][1] + bse),
                    (H16)(acc[i][j][2] + bse), (H16)(acc[i][j][3] + bse)};
        *(half4*)&vto[((size_t)(bbx * NH + h) * HW + wcol) * S + s0] = v4;
      } else {
#pragma unroll
        for (int r = 0; r < 4; ++r) {
          int row = bm + wm + i * 16 + g * 4 + r;
          float val = acc[i][j][r] + bse;
          int bbx = row >> 11, s = row & (S - 1);
          size_t bh = (size_t)(bbx * NH + h);
          if (z == 0)
            qo[(bh * S + s) * HW + wcol] = (H16)val;
          else
            ko[(bh * S + s) * HW + wcol] = (H16)val;
        }
      }
    }
  }
}

// ---------------- flash attention v9: LDS diet ------------------------------
// K: LDS double-buffered (staged via XOR-swizzled b128, conflict-free floor).
// V: NEVER staged — frags read straight from global (L2-resident, 2MB/XCD),
//    register double-buffered one chunk ahead (vA/vB, manual 2x unroll).
// P: PSTR=64 with XOR-8-unit swizzle -> write 2-way (free), read at the
//    8-lane/quad floor. Kills the 3.1M bank conflicts of the PSTR=72 layout.
// Q pre-scaled by 1/sqrt(64)*log2e in fp16 -> exp2 arg is the raw MFMA out.
// LDS/wave-iter: K-frag 8K + P 8K + K-stage 2K = 18K (was 28K).
__global__ __launch_bounds__(256, 2) void attn(const H16* __restrict__ q,
                                               const H16* __restrict__ k,
                                               const H16* __restrict__ vt,
                                               float* __restrict__ out) {
  constexpr int NIT = S / 64;  // 32
  __shared__ __align__(16) H16 Ks[2][64 * 64];  // 16 KB
  __shared__ __align__(16) H16 pl[4][32 * 64];  // 16 KB

  const int id = blockIdx.x;  // 512 blocks
  const int xcd = id & 7, slot = id >> 3;
  const int bh = xcd * 4 + (slot >> 4);  // 4 heads per XCD
  const int qt = slot & 15;              // 16 q-tiles of 128

  const int t = threadIdx.x, wave = t >> 6, lane = t & 63;
  const int g = lane >> 4, c = lane & 15;
  const int q0 = qt * 128 + wave * 32;
  const H16* qp = q + ((size_t)bh * S + q0) * HW;
  const H16* kp = k + (size_t)bh * S * HW;
  const H16* vp = vt + (size_t)bh * HW * S;

  // K staging map: unit u: row=u>>3, k8=u&7; thread t owns u=t, u=t+256
  const int r0 = t >> 3, k8 = t & 7;
  const int r1 = r0 + 32;
  const int wsw0 = r0 * 64 + ((k8 ^ (r0 & 7)) * 8);
  const int wsw1 = r1 * 64 + ((k8 ^ (r1 & 7)) * 8);

  // Q^T B-frags, pre-scaled by sc (fold of 1/sqrt(64) * log2(e))
  const H16 scq = (H16)(0.125f * 1.44269504088896f);
  half8 qb[2][2];
#pragma unroll
  for (int qg = 0; qg < 2; ++qg) {
    qb[qg][0] = *(const half8*)&qp[(qg * 16 + c) * HW + g * 8];
    qb[qg][1] = *(const half8*)&qp[(qg * 16 + c) * HW + 32 + g * 8];
#pragma unroll
    for (int e = 0; e < 8; ++e) {
      qb[qg][0][e] *= scq;
      qb[qg][1][e] *= scq;
    }
  }

  f32x4 o[4][2] = {};
  float l[2] = {0.f, 0.f};
  H16* myp = pl[wave];

  // swizzled fragment read offsets (shared by K tiles and P buffer)
  const int sw0 = (g ^ (c & 7)) * 8;
  const int sw1 = ((4 + g) ^ (c & 7)) * 8;
  // P write columns: key-quad kt,g -> 8-unit u=kt*2+(g>>1), offset (g&1)*4
  int pwc[4];
#pragma unroll
  for (int kt = 0; kt < 4; ++kt)
    pwc[kt] = (((kt * 2 + (g >> 1)) ^ (c & 7)) * 8) + (g & 1) * 4;

  // V row pointers (A-frag rows w = wt*16 + c)
  const H16* vrow[4];
#pragma unroll
  for (int wt = 0; wt < 4; ++wt) vrow[wt] = vp + (size_t)(wt * 16 + c) * S;

  // prologue: stage K chunk 0 -> Ks[0]; V frags chunk 0 -> vA
  {
    half8 ka = *(const half8*)&kp[(size_t)r0 * HW + k8 * 8];
    half8 kb = *(const half8*)&kp[(size_t)r1 * HW + k8 * 8];
    *(half8*)&Ks[0][wsw0] = ka;
    *(half8*)&Ks[0][wsw1] = kb;
  }
  half8 vA[4][2], vB[4][2];
#pragma unroll
  for (int wt = 0; wt < 4; ++wt) {
    vA[wt][0] = *(const half8*)&vrow[wt][g * 8];
    vA[wt][1] = *(const half8*)&vrow[wt][32 + g * 8];
  }

#define ATTN_ITER(IT, VCUR, VNXT, PAR)                                        \
  {                                                                           \
    __syncthreads();                                                          \
    const bool more = (IT) + 1 < NIT;                                         \
    const int nck = ((IT) + 1) * 64;                                          \
    half8 nka, nkb;                                                           \
    if (more) {                                                               \
      nka = *(const half8*)&kp[(size_t)(nck + r0) * HW + k8 * 8];             \
      nkb = *(const half8*)&kp[(size_t)(nck + r1) * HW + k8 * 8];             \
      _Pragma("unroll") for (int wt = 0; wt < 4; ++wt) {                      \
        VNXT[wt][0] = *(const half8*)&vrow[wt][nck + g * 8];                  \
        VNXT[wt][1] = *(const half8*)&vrow[wt][nck + 32 + g * 8];             \
      }                                                                       \
    }                                                                         \
    const H16* ks = Ks[PAR];                                                  \
    f32x4 st[4][2];                                                           \
    _Pragma("unroll") for (int kt = 0; kt < 4; ++kt) {                        \
      const H16* kr = &ks[(kt * 16 + c) * 64];                                \
      half8 ka0 = *(const half8*)&kr[sw0];                                    \
      half8 ka1 = *(const half8*)&kr[sw1];                                    \
      _Pragma("unroll") for (int qg = 0; qg < 2; ++qg) {                      \
        f32x4 zz = {};                                                        \
        st[kt][qg] = __builtin_amdgcn_mfma_f32_16x16x32_f16(                  \
            ka0, qb[qg][0], zz, 0, 0, 0);                                     \
        st[kt][qg] = __builtin_amdgcn_mfma_f32_16x16x32_f16(                  \
            ka1, qb[qg][1], st[kt][qg], 0, 0, 0);                             \
      }                                                                       \
    }                                                                         \
    half8 pb[2][2];                                                           \
    _Pragma("unroll") for (int qg = 0; qg < 2; ++qg) {                        \
      _Pragma("unroll") for (int kt = 0; kt < 4; ++kt) {                      \
        float p0 = __builtin_amdgcn_exp2f(st[kt][qg][0]);                     \
        float p1 = __builtin_amdgcn_exp2f(st[kt][qg][1]);                     \
        float p2 = __builtin_amdgcn_exp2f(st[kt][qg][2]);                     \
        float p3 = __builtin_amdgcn_exp2f(st[kt][qg][3]);                     \
        l[qg] += (p0 + p1) + (p2 + p3);                                       \
        half4 pk = {(H16)p0, (H16)p1, (H16)p2, (H16)p3};                      \
        *(half4*)&myp[(qg * 16 + c) * 64 + pwc[kt]] = pk;                     \
      }                                                                       \
      pb[qg][0] = *(const half8*)&myp[(qg * 16 + c) * 64 + sw0];              \
      pb[qg][1] = *(const half8*)&myp[(qg * 16 + c) * 64 + sw1];              \
    }                                                                         \
    _Pragma("unroll") for (int wt = 0; wt < 4; ++wt) {                        \
      _Pragma("unroll") for (int qg = 0; qg < 2; ++qg) {                      \
        o[wt][qg] = __builtin_amdgcn_mfma_f32_16x16x32_f16(                   \
            VCUR[wt][0], pb[qg][0], o[wt][qg], 0, 0, 0);                      \
        o[wt][qg] = __builtin_amdgcn_mfma_f32_16x16x32_f16(                   \
            VCUR[wt][1], pb[qg][1], o[wt][qg], 0, 0, 0);                      \
      }                                                                       \
    }                                                                         \
    if (more) {                                                               \
      H16* kd = Ks[(PAR) ^ 1];                                                \
      *(half8*)&kd[wsw0] = nka;                                               \
      *(half8*)&kd[wsw1] = nkb;                                               \
    }                                                                         \
  }

  for (int itp = 0; itp < NIT; itp += 2) {
    ATTN_ITER(itp, vA, vB, 0)
    ATTN_ITER(itp + 1, vB, vA, 1)
  }
#undef ATTN_ITER

  // final l reduce across the 4 g-lane groups (lane bits 4,5)
#pragma unroll
  for (int qg = 0; qg < 2; ++qg) {
    l[qg] += __shfl_xor(l[qg], 16, 64);
    l[qg] += __shfl_xor(l[qg], 32, 64);
  }

  const int bbx = bh >> 4, h = bh & 15;
#pragma unroll
  for (int qg = 0; qg < 2; ++qg) {
    const float inv = 1.0f / l[qg];
    float* orow = out + ((size_t)bbx * S + q0 + qg * 16 + c) * D + h * HW;
#pragma unroll
    for (int wt = 0; wt < 4; ++wt) {
      float4 v4 = {o[wt][qg][0] * inv, o[wt][qg][1] * inv, o[wt][qg][2] * inv,
                   o[wt][qg][3] * inv};
      *(float4*)&orow[wt * 16 + g * 4] = v4;
    }
  }
}

extern "C" void kernel_launch(void* const* d_in, const int* in_sizes, int n_in,
                              void* d_out, int out_size, void* d_ws,
                              size_t ws_size, hipStream_t stream) {
  const float* x = (const float*)d_in[0];
  const float* Wq = (const float*)d_in[1];
  const float* bq = (const float*)d_in[2];
  const float* Wk = (const float*)d_in[3];
  const float* bk = (const float*)d_in[4];
  const float* Wv = (const float*)d_in[5];
  const float* bv = (const float*)d_in[6];
  float* out = (float*)d_out;
  char* ws = (char*)d_ws;
  H16* xh = (H16*)(ws + XH_OFF);
  H16* wt = (H16*)(ws + WT_OFF);
  H16* qw = (H16*)(ws + Q_OFF);
  H16* kw = (H16*)(ws + K_OFF);
  H16* vtw = (H16*)(ws + VT_OFF);

  cvt_x<<<dim3((M * D) / (256 * 8)), 256, 0, stream>>>(x, xh);
  wt_cvt<<<dim3(16, 16, 3), 256, 0, stream>>>(Wq, Wk, Wv, wt);
  qkv_gemm<<<dim3(8, 32, 3), 256, 0, stream>>>(xh, wt, bq, bk, bv, qw, kw, vtw);
  attn<<<dim3(512), 256, 0, stream>>>(qw, kw, vtw, out);
}

// Round 10
// 166.012 us; speedup vs baseline: 1.1443x; 1.1443x over previous
//
#include <hip/hip_runtime.h>

typedef _Float16 H16;
typedef _Float16 half8 __attribute__((ext_vector_type(8)));
typedef _Float16 half4 __attribute__((ext_vector_type(4)));
typedef float f32x4 __attribute__((ext_vector_type(4)));

// problem dims
constexpr int Bb = 2, S = 2048, D = 1024, NH = 16, HW = 64;
constexpr int M = Bb * S;  // 4096

// workspace layout (bytes)
constexpr size_t XH_OFF = 0;                               // [M][D] f16
constexpr size_t WT_OFF = XH_OFF + (size_t)M * D * 2;      // 3x [D(n)][D(k)] f16
constexpr size_t Q_OFF  = WT_OFF + 3ull * D * D * 2;       // [B][NH][S][HW] f16
constexpr size_t K_OFF  = Q_OFF + (size_t)M * D * 2;       // [B][NH][S][HW] f16
constexpr size_t VT_OFF = K_OFF + (size_t)M * D * 2;       // [B][NH][HW][S] f16

#define GLOAD_LDS16(g, l)                                        \
  __builtin_amdgcn_global_load_lds(                              \
      (const __attribute__((address_space(1))) void*)(g),        \
      (__attribute__((address_space(3))) void*)(l), 16, 0, 0)

// ---------------- fused prep: x fp32->fp16 (z=0) + W^T fp16 (z=1..3) --------
__global__ __launch_bounds__(256) void prep(const float* __restrict__ x,
                                            H16* __restrict__ xh,
                                            const float* __restrict__ w0,
                                            const float* __restrict__ w1,
                                            const float* __restrict__ w2,
                                            H16* __restrict__ wt) {
  __shared__ H16 tile[64][65];
  const int z = blockIdx.z;
  const int t = threadIdx.x;
  if (z == 0) {
    // 256 blocks, each converts 8 chunks of 2048 f16
    const int bid = blockIdx.y * 16 + blockIdx.x;
#pragma unroll
    for (int r = 0; r < 8; ++r) {
      size_t i = ((size_t)(bid * 8 + r) * 256 + t) * 8;
      float4 a = *(const float4*)(x + i);
      float4 b = *(const float4*)(x + i + 4);
      half8 h = {(H16)a.x, (H16)a.y, (H16)a.z, (H16)a.w,
                 (H16)b.x, (H16)b.y, (H16)b.z, (H16)b.w};
      *(half8*)(xh + i) = h;
    }
  } else {
    const float* w = z == 1 ? w0 : z == 2 ? w1 : w2;
    H16* out = wt + (size_t)(z - 1) * D * D;
    int c = t & 63, r4 = t >> 6;
    int bx = blockIdx.x * 64, by = blockIdx.y * 64;
#pragma unroll 4
    for (int it = 0; it < 16; ++it) {
      int row = it * 4 + r4;
      tile[c][row] = (H16)w[(size_t)(by + row) * D + bx + c];
    }
    __syncthreads();
#pragma unroll 4
    for (int it = 0; it < 16; ++it) {
      int row = it * 4 + r4;
      out[(size_t)(bx + row) * D + by + c] = tile[row][c];
    }
  }
}

// ---------------- fused QKV GEMM (fp16 MFMA, 128x128x32 tiles) ----------------
__global__ __launch_bounds__(256) void qkv_gemm(
    const H16* __restrict__ xh, const H16* __restrict__ wt,
    const float* __restrict__ bq, const float* __restrict__ bk,
    const float* __restrict__ bv, H16* __restrict__ qo, H16* __restrict__ ko,
    H16* __restrict__ vto) {
  __shared__ __align__(16) H16 As[128 * 32];
  __shared__ __align__(16) H16 Bs[128 * 32];
  const int z = blockIdx.z;
  const H16* w = wt + (size_t)z * D * D;
  const float* bias = z == 0 ? bq : z == 1 ? bk : bv;
  const int bm = blockIdx.y * 128, bn = blockIdx.x * 128;
  const int t = threadIdx.x;
  const int wave = t >> 6, lane = t & 63;
  const int g = lane >> 4, c = lane & 15;
  const int wm = (wave >> 1) * 64, wn = (wave & 1) * 64;

  f32x4 acc[4][4] = {};

  for (int kk = 0; kk < D; kk += 32) {
#pragma unroll
    for (int rnd = 0; rnd < 2; ++rnd) {
      int cid = rnd * 256 + t;
      int row = cid >> 2, k0 = (cid & 3) * 8;
      GLOAD_LDS16(&xh[(size_t)(bm + row) * D + kk + k0], &As[cid * 8]);
      GLOAD_LDS16(&w[(size_t)(bn + row) * D + kk + k0], &Bs[cid * 8]);
    }
    __syncthreads();
    half8 af[4], bf[4];
#pragma unroll
    for (int i = 0; i < 4; ++i) {
      af[i] = *(const half8*)&As[(wm + i * 16 + c) * 32 + g * 8];
      bf[i] = *(const half8*)&Bs[(wn + i * 16 + c) * 32 + g * 8];
    }
#pragma unroll
    for (int i = 0; i < 4; ++i)
#pragma unroll
      for (int j = 0; j < 4; ++j)
        acc[i][j] =
            __builtin_amdgcn_mfma_f32_16x16x32_f16(af[i], bf[j], acc[i][j], 0, 0, 0);
    __syncthreads();
  }

#pragma unroll
  for (int i = 0; i < 4; ++i) {
#pragma unroll
    for (int j = 0; j < 4; ++j) {
      int coln = bn + wn + j * 16 + c;
      float bse = bias[coln];
      int h = coln >> 6, wcol = coln & 63;
      if (z == 2) {
        int row0 = bm + wm + i * 16 + g * 4;
        int bbx = row0 >> 11, s0 = row0 & (S - 1);
        half4 v4 = {(H16)(acc[i][j][0] + bse), (H16)(acc[i][j][1] + bse),
                    (H16)(acc[i][j][2] + bse), (H16)(acc[i][j][3] + bse)};
        *(half4*)&vto[((size_t)(bbx * NH + h) * HW + wcol) * S + s0] = v4;
      } else {
#pragma unroll
        for (int r = 0; r < 4; ++r) {
          int row = bm + wm + i * 16 + g * 4 + r;
          float val = acc[i][j][r] + bse;
          int bbx = row >> 11, s = row & (S - 1);
          size_t bh = (size_t)(bbx * NH + h);
          if (z == 0)
            qo[(bh * S + s) * HW + wcol] = (H16)val;
          else
            ko[(bh * S + s) * HW + wcol] = (H16)val;
        }
      }
    }
  }
}

// ---------------- flash attention v10: v6 + swizzled P + prescaled Q --------
// v6 structure (best measured: K/V LDS dbuf, no online max, per-lane l
// partials) with the two R9-verified micro-wins:
//  - P buffer PSTR=64, XOR-8-unit swizzle (write 2-way free, read at the
//    b128 floor) — removes the PSTR=72 4-way write conflicts.
//  - Q fragments pre-scaled by 1/sqrt(64)*log2e (exp2 arg = raw MFMA out).
// LDS 48KB. 512 blocks XCD-swizzled, 4 waves, 32 q/wave, 64 keys/iter.
__global__ __launch_bounds__(256, 2) void attn(const H16* __restrict__ q,
                                               const H16* __restrict__ k,
                                               const H16* __restrict__ vt,
                                               float* __restrict__ out) {
  constexpr int NIT = S / 64;  // 32
  __shared__ __align__(16) H16 Ks[2][64 * 64];
  __shared__ __align__(16) H16 Vs[2][64 * 64];
  __shared__ __align__(16) H16 pl[4][32 * 64];

  const int id = blockIdx.x;  // 512 blocks
  const int xcd = id & 7, slot = id >> 3;
  const int bh = xcd * 4 + (slot >> 4);  // 4 heads per XCD
  const int qt = slot & 15;              // 16 q-tiles of 128

  const int t = threadIdx.x, wave = t >> 6, lane = t & 63;
  const int g = lane >> 4, c = lane & 15;
  const int q0 = qt * 128 + wave * 32;
  const H16* qp = q + ((size_t)bh * S + q0) * HW;
  const H16* kp = k + (size_t)bh * S * HW;
  const H16* vp = vt + (size_t)bh * HW * S;

  // staging map: unit u in [0,512): row=u>>3, k8=u&7; thread t owns u=t, t+256
  const int r0 = t >> 3, k8 = t & 7;
  const int r1 = r0 + 32;
  const int wsw0 = r0 * 64 + ((k8 ^ (r0 & 7)) * 8);
  const int wsw1 = r1 * 64 + ((k8 ^ (r1 & 7)) * 8);

  // Q^T B-frags, 2 query groups, pre-scaled
  const H16 scq = (H16)(0.125f * 1.44269504088896f);
  half8 qb[2][2];
#pragma unroll
  for (int qg = 0; qg < 2; ++qg) {
    qb[qg][0] = *(const half8*)&qp[(qg * 16 + c) * HW + g * 8];
    qb[qg][1] = *(const half8*)&qp[(qg * 16 + c) * HW + 32 + g * 8];
#pragma unroll
    for (int e = 0; e < 8; ++e) {
      qb[qg][0][e] *= scq;
      qb[qg][1][e] *= scq;
    }
  }

  f32x4 o[4][2] = {};
  float l[2] = {0.f, 0.f};
  H16* myp = pl[wave];

  // swizzled fragment read offsets (tiles 16-aligned so row&7 == c&7)
  const int sw0 = (g ^ (c & 7)) * 8;
  const int sw1 = ((4 + g) ^ (c & 7)) * 8;
  // P write columns: key 8-unit u=kt*2+(g>>1), intra-unit offset (g&1)*4
  int pwc[4];
#pragma unroll
  for (int kt = 0; kt < 4; ++kt)
    pwc[kt] = (((kt * 2 + (g >> 1)) ^ (c & 7)) * 8) + (g & 1) * 4;

  // prologue: stage chunk 0 into buf 0
  {
    half8 ka = *(const half8*)&kp[(size_t)r0 * HW + k8 * 8];
    half8 kb = *(const half8*)&kp[(size_t)r1 * HW + k8 * 8];
    half8 va = *(const half8*)&vp[(size_t)r0 * S + k8 * 8];
    half8 vb = *(const half8*)&vp[(size_t)r1 * S + k8 * 8];
    *(half8*)&Ks[0][wsw0] = ka;
    *(half8*)&Ks[0][wsw1] = kb;
    *(half8*)&Vs[0][wsw0] = va;
    *(half8*)&Vs[0][wsw1] = vb;
  }

  int buf = 0;
  for (int it = 0; it < NIT; ++it) {
    __syncthreads();

    // prefetch next chunk into registers (overlaps compute)
    half8 nka, nkb, nva, nvb;
    if (it + 1 < NIT) {
      const int nck = (it + 1) * 64;
      nka = *(const half8*)&kp[(size_t)(nck + r0) * HW + k8 * 8];
      nkb = *(const half8*)&kp[(size_t)(nck + r1) * HW + k8 * 8];
      nva = *(const half8*)&vp[(size_t)r0 * S + nck + k8 * 8];
      nvb = *(const half8*)&vp[(size_t)r1 * S + nck + k8 * 8];
    }

    const H16* ks = Ks[buf];
    const H16* vs = Vs[buf];

    // S^T tiles: st[kt][qg], K frags shared across query groups
    f32x4 st[4][2];
#pragma unroll
    for (int kt = 0; kt < 4; ++kt) {
      const H16* kr = &ks[(kt * 16 + c) * 64];
      half8 ka0 = *(const half8*)&kr[sw0];
      half8 ka1 = *(const half8*)&kr[sw1];
#pragma unroll
      for (int qg = 0; qg < 2; ++qg) {
        f32x4 z = {};
        st[kt][qg] =
            __builtin_amdgcn_mfma_f32_16x16x32_f16(ka0, qb[qg][0], z, 0, 0, 0);
        st[kt][qg] = __builtin_amdgcn_mfma_f32_16x16x32_f16(ka1, qb[qg][1],
                                                            st[kt][qg], 0, 0, 0);
      }
    }

    // p = exp2(raw); per-lane l partial; pack to fp16; swizzled P round-trip
    half8 pb[2][2];
#pragma unroll
    for (int qg = 0; qg < 2; ++qg) {
#pragma unroll
      for (int kt = 0; kt < 4; ++kt) {
        float p0 = __builtin_amdgcn_exp2f(st[kt][qg][0]);
        float p1 = __builtin_amdgcn_exp2f(st[kt][qg][1]);
        float p2 = __builtin_amdgcn_exp2f(st[kt][qg][2]);
        float p3 = __builtin_amdgcn_exp2f(st[kt][qg][3]);
        l[qg] += (p0 + p1) + (p2 + p3);
        half4 pk = {(H16)p0, (H16)p1, (H16)p2, (H16)p3};
        *(half4*)&myp[(qg * 16 + c) * 64 + pwc[kt]] = pk;
      }
      pb[qg][0] = *(const half8*)&myp[(qg * 16 + c) * 64 + sw0];
      pb[qg][1] = *(const half8*)&myp[(qg * 16 + c) * 64 + sw1];
    }

    // O^T += V^T · P, V frags shared across query groups
#pragma unroll
    for (int wt = 0; wt < 4; ++wt) {
      const H16* vr = &vs[(wt * 16 + c) * 64];
      half8 va0 = *(const half8*)&vr[sw0];
      half8 va1 = *(const half8*)&vr[sw1];
#pragma unroll
      for (int qg = 0; qg < 2; ++qg) {
        o[wt][qg] = __builtin_amdgcn_mfma_f32_16x16x32_f16(va0, pb[qg][0],
                                                           o[wt][qg], 0, 0, 0);
        o[wt][qg] = __builtin_amdgcn_mfma_f32_16x16x32_f16(va1, pb[qg][1],
                                                           o[wt][qg], 0, 0, 0);
      }
    }

    // tail: stage prefetched chunk into the other buffer
    if (it + 1 < NIT) {
      H16* kd = Ks[buf ^ 1];
      H16* vd = Vs[buf ^ 1];
      *(half8*)&kd[wsw0] = nka;
      *(half8*)&kd[wsw1] = nkb;
      *(half8*)&vd[wsw0] = nva;
      *(half8*)&vd[wsw1] = nvb;
    }
    buf ^= 1;
  }

  // final l reduce across the 4 g-lane groups (lane bits 4,5)
#pragma unroll
  for (int qg = 0; qg < 2; ++qg) {
    l[qg] += __shfl_xor(l[qg], 16, 64);
    l[qg] += __shfl_xor(l[qg], 32, 64);
  }

  const int bbx = bh >> 4, h = bh & 15;
#pragma unroll
  for (int qg = 0; qg < 2; ++qg) {
    const float inv = 1.0f / l[qg];
    float* orow = out + ((size_t)bbx * S + q0 + qg * 16 + c) * D + h * HW;
#pragma unroll
    for (int wt = 0; wt < 4; ++wt) {
      float4 v4 = {o[wt][qg][0] * inv, o[wt][qg][1] * inv, o[wt][qg][2] * inv,
                   o[wt][qg][3] * inv};
      *(float4*)&orow[wt * 16 + g * 4] = v4;
    }
  }
}

extern "C" void kernel_launch(void* const* d_in, const int* in_sizes, int n_in,
                              void* d_out, int out_size, void* d_ws,
                              size_t ws_size, hipStream_t stream) {
  const float* x = (const float*)d_in[0];
  const float* Wq = (const float*)d_in[1];
  const float* bq = (const float*)d_in[2];
  const float* Wk = (const float*)d_in[3];
  const float* bk = (const float*)d_in[4];
  const float* Wv = (const float*)d_in[5];
  const float* bv = (const float*)d_in[6];
  float* out = (float*)d_out;
  char* ws = (char*)d_ws;
  H16* xh = (H16*)(ws + XH_OFF);
  H16* wt = (H16*)(ws + WT_OFF);
  H16* qw = (H16*)(ws + Q_OFF);
  H16* kw = (H16*)(ws + K_OFF);
  H16* vtw = (H16*)(ws + VT_OFF);

  prep<<<dim3(16, 16, 4), 256, 0, stream>>>(x, xh, Wq, Wk, Wv, wt);
  qkv_gemm<<<dim3(8, 32, 3), 256, 0, stream>>>(xh, wt, bq, bk, bv, qw, kw, vtw);
  attn<<<dim3(512), 256, 0, stream>>>(qw, kw, vtw, out);
}